// Round 1
// baseline (71.023 us; speedup 1.0000x reference)
//
#include <hip/hip_runtime.h>

#define ALPHA 0.2f

constexpr int N = 1024;
constexpr int F = 64;
constexpr int TI = 4;          // rows per block
constexpr int NT = 1024;       // threads per block = 16 waves
constexpr int NW = NT / 64;

// Fully fused GAT layer: one kernel, 256 blocks x 1024 threads, 4 rows/block.
// Per block: recompute w1=W@a1, w2=W@a2 (8 KFLOP, trivial); per wave: e2 for its
// own 64 attention columns (cooperative coalesced loads), p slice in its own LDS
// region (same-wave produce->consume, lgkmcnt only, no block barrier), then the
// att@h sweep. Epilogue reduces across waves, derives denominators from pws,
// normalizes, applies @W and elu.
__global__ __launch_bounds__(NT) void gat_fused(
    const float* __restrict__ h,
    const int* __restrict__ adj,
    const float* __restrict__ W,
    const float* __restrict__ a,
    float* __restrict__ out) {

  const int t = threadIdx.x;
  const int wave = t >> 6;
  const int lane = t & 63;
  const int i0 = blockIdx.x * TI;
  const int j = t;                       // this thread's attention column

  __shared__ float w1s[F], w2s[F];       // 0.5 KB
  __shared__ float e2s[NW][64];          // 4 KB   (per-wave slices)
  __shared__ float pws[NW][TI][64];      // 16 KB  (per-wave exp-weights)
  __shared__ float accs[NW][TI][F];      // 16 KB
  __shared__ float us[TI][F];            // 1 KB

  // ---- prefetch: adj (4 coalesced dwords) + e1 h-rows, issued before any LDS wait ----
  int ad[TI];
  float hvr[TI];
  #pragma unroll
  for (int r = 0; r < TI; ++r) {
    ad[r]  = adj[(size_t)(i0 + r) * N + j];
    hvr[r] = h[(size_t)(i0 + r) * F + lane];
  }

  // ---- w1 = W@a1, w2 = W@a2 : thread t<256 covers row f=t>>2, 16 cols ----
  if (t < 256) {
    const int f = t >> 2;
    const int c0 = (t & 3) * 16;
    float s1 = 0.f, s2 = 0.f;
    #pragma unroll
    for (int q = 0; q < 4; ++q) {
      const float4 wv  = *(const float4*)&W[f * F + c0 + q * 4];
      const float4 a1v = *(const float4*)&a[c0 + q * 4];
      const float4 a2v = *(const float4*)&a[F + c0 + q * 4];
      s1 += wv.x*a1v.x + wv.y*a1v.y + wv.z*a1v.z + wv.w*a1v.w;
      s2 += wv.x*a2v.x + wv.y*a2v.y + wv.z*a2v.z + wv.w*a2v.w;
    }
    s1 += __shfl_down(s1, 2); s1 += __shfl_down(s1, 1);
    s2 += __shfl_down(s2, 2); s2 += __shfl_down(s2, 1);
    if ((t & 3) == 0) { w1s[f] = s1; w2s[f] = s2; }
  }
  __syncthreads();                       // B1: w1s/w2s ready

  // ---- e1 for the block's 4 rows: butterfly, redundant per wave (no barrier) ----
  float e1r[TI];
  #pragma unroll
  for (int r = 0; r < TI; ++r) {
    float v = hvr[r] * w1s[lane];
    #pragma unroll
    for (int off = 32; off > 0; off >>= 1) v += __shfl_xor(v, off);
    e1r[r] = v;
  }

  // ---- e2 for THIS wave's 64 columns: 4-lane clusters, coalesced h reads ----
  {
    const int sub = lane >> 2;           // row within pass
    const int qf  = (lane & 3) << 4;     // f-quarter: 0,16,32,48
    #pragma unroll
    for (int pass = 0; pass < 4; ++pass) {
      const int row = (wave << 6) + (pass << 4) + sub;
      const float* hr = &h[(size_t)row * F + qf];
      float s = 0.f;
      #pragma unroll
      for (int q = 0; q < 4; ++q) {
        const float4 hv = *(const float4*)&hr[q * 4];
        const float4 wv = *(const float4*)&w2s[qf + q * 4];
        s += hv.x*wv.x + hv.y*wv.y + hv.z*wv.z + hv.w*wv.w;
      }
      s += __shfl_down(s, 2);
      s += __shfl_down(s, 1);
      if ((lane & 3) == 0) e2s[wave][(pass << 4) + sub] = s;
    }
  }
  // same-wave LDS produce->consume: lgkmcnt drain is sufficient, no barrier
  asm volatile("s_waitcnt lgkmcnt(0)" ::: "memory");
  const float e2v = e2s[wave][lane];

  // ---- p slice: pws[wave][r][lane] = adj ? exp(leaky(e1+e2)) : 0 ----
  #pragma unroll
  for (int r = 0; r < TI; ++r) {
    float s = e1r[r] + e2v;
    s = (s > 0.f) ? s : ALPHA * s;
    pws[wave][r][lane] = (ad[r] > 0) ? __expf(s) : 0.f;
  }
  asm volatile("s_waitcnt lgkmcnt(0)" ::: "memory");

  // ---- sweep: acc[r][lane] += sum over this wave's own 64 j ----
  {
    float a0 = 0.f, a1 = 0.f, a2 = 0.f, a3 = 0.f;
    const float* hb = h + (size_t)(wave << 6) * F + lane;
    #pragma unroll 4
    for (int jc = 0; jc < 64; jc += 4) {
      const float4 q0 = *(const float4*)&pws[wave][0][jc];   // wave-uniform: broadcast
      const float4 q1 = *(const float4*)&pws[wave][1][jc];
      const float4 q2 = *(const float4*)&pws[wave][2][jc];
      const float4 q3 = *(const float4*)&pws[wave][3][jc];
      #pragma unroll
      for (int u = 0; u < 4; ++u) {
        const float hv = hb[(size_t)(jc + u) * F];           // coalesced, L2-hot
        a0 += (&q0.x)[u] * hv;
        a1 += (&q1.x)[u] * hv;
        a2 += (&q2.x)[u] * hv;
        a3 += (&q3.x)[u] * hv;
      }
    }
    accs[wave][0][lane] = a0;
    accs[wave][1][lane] = a1;
    accs[wave][2][lane] = a2;
    accs[wave][3][lane] = a3;
  }
  __syncthreads();                       // B2: accs + pws visible block-wide

  // ---- epilogue A: reduce 16 waves, denominators from pws, normalize ----
  if (t < TI * F) {
    const int rr = t >> 6;               // wave 0..3 owns row rr
    const int f = t & 63;
    float su = 0.f, ps = 0.f;
    #pragma unroll
    for (int w = 0; w < NW; ++w) {
      su += accs[w][rr][f];
      ps += pws[w][rr][f];
    }
    #pragma unroll
    for (int off = 32; off > 0; off >>= 1) ps += __shfl_xor(ps, off);
    us[rr][f] = su / ps;
  }
  __syncthreads();                       // B3

  // ---- epilogue B: out[r][g] = elu( us[r][:] @ W[:][g] ) ----
  if (t < TI * F) {
    const int rr = t >> 6;
    const int g = t & 63;
    float acc = 0.f;
    #pragma unroll
    for (int f = 0; f < F; ++f)
      acc += us[rr][f] * W[f * F + g];   // us broadcast; W coalesced
    out[(size_t)(i0 + rr) * F + g] = (acc > 0.f) ? acc : expm1f(acc);
  }
}

extern "C" void kernel_launch(void* const* d_in, const int* in_sizes, int n_in,
                              void* d_out, int out_size, void* d_ws, size_t ws_size,
                              hipStream_t stream) {
  const float* h   = (const float*)d_in[0];
  const int*   adj = (const int*)d_in[1];
  const float* W   = (const float*)d_in[2];
  const float* a   = (const float*)d_in[3];
  float* out       = (float*)d_out;

  gat_fused<<<N / TI, NT, 0, stream>>>(h, adj, W, a, out);
}